// Round 4
// baseline (530.545 us; speedup 1.0000x reference)
//
#include <hip/hip_runtime.h>
#include <cstdint>
#include <cstddef>

#define NLAB 128
#define TT   512
#define BB   512
#define MB   16        // batches per forward block
#define PAD_ 0
#define BOS_ 1
#define EOS_ 2
#define LN2F  0.6931471805599453f
#define LOG2E 1.4426950408889634f

typedef float f32x4 __attribute__((ext_vector_type(4)));
typedef short s16x8 __attribute__((ext_vector_type(8)));

#if __has_builtin(__builtin_amdgcn_exp2f)
#define EXP2F(x) __builtin_amdgcn_exp2f(x)
#else
#define EXP2F(x) exp2f(x)
#endif

#define MFMA_(A,B,CV) __builtin_amdgcn_mfma_f32_16x16x32_bf16((A),(B),(CV),0,0,0)

// ---- mask dtype hedge: bool(1B) vs int32(4B) -------------------------------
__device__ __forceinline__ bool mask_is_i32(const unsigned char* m8) {
    return m8[1] == 0;   // mask[0][1] always true; int32 high byte => 0
}
__device__ __forceinline__ bool mask_at(const unsigned char* m8, int idx, bool isi) {
    if (isi) return ((const int*)m8)[idx] != 0;
    return m8[idx] != 0;
}

__device__ __forceinline__ unsigned f2bf(float f) {
    union { float f; unsigned u; } v; v.f = f;
    return (v.u + 0x7FFFu + ((v.u >> 16) & 1u)) >> 16;   // RNE; inputs finite >= 0
}
__device__ __forceinline__ unsigned cvtpk(float lo, float hi) {   // bf16 pair, RNE
    unsigned r;
    asm("v_cvt_pk_bf16_f32 %0, %1, %2" : "=v"(r) : "v"(lo), "v"(hi));
    return r;
}

// ============================================================================
// Fused kernel, 256 threads/block.
//   blocks [0, 32):    forward scan, 4 waves (1/SIMD).  Wave w owns M-tiles
//                      {w, w+4}.  One __syncthreads per step (proven).
//                      Chain cuts vs r3: (1) per-step paired feature reload at
//                      step TOP (slot consumed this step reloads f(t+8); a
//                      full step elapses before the barrier's vmcnt(0) drain
//                      -> HBM latency hidden); (2) rescale exponent read
//                      directly via ds_read_u16 of bf16 p[3][c] in parallel
//                      with b-frag reads (no serial shfl); (3) 8 independent
//                      MFMAs + pairwise tree add (1x mfma latency); (4) ring
//                      stores EF=exp2(f*log2e), converted one step ahead.
//   blocks [32, 160):  gold score + length, 4 batches/block (1 per wave).
// ============================================================================
__global__ __launch_bounds__(256, 1) void crf_fused(
        const float* __restrict__ feats,
        const int*   __restrict__ tags,
        const unsigned char* __restrict__ m8,
        const float* __restrict__ tr,
        float* __restrict__ gold_out,
        float* __restrict__ logZ_out) {
    const int bx  = blockIdx.x;
    const int tid = threadIdx.x;
    const bool isi = mask_is_i32(m8);

    if (bx >= BB / MB) {
        // ---------------- gold path: 4 batches per block ---------------------
        const int b    = (bx - BB / MB) * 4 + (tid >> 6);
        const int lane = tid & 63;
        const size_t fb = (size_t)b * TT * NLAB;
        float gp = 0.f; int cnt = 0;
        for (int tt = lane; tt < TT; tt += 64) {
            const int idx = b * TT + tt;
            const bool mm = mask_at(m8, idx, isi);
            cnt += mm ? 1 : 0;
            const int tg = tags[idx];
            if (tt == 0) gp += feats[fb + tg] + tr[BOS_ * NLAB + tg];
            else if (mm) gp += feats[fb + (size_t)tt * NLAB + tg]
                             + tr[tags[idx - 1] * NLAB + tg];
        }
        #pragma unroll
        for (int off = 32; off > 0; off >>= 1) {
            gp  += __shfl_xor(gp,  off, 64);
            cnt += __shfl_xor(cnt, off, 64);
        }
        if (lane == 0)
            gold_out[b] = gp + tr[tags[b * TT + cnt - 1] * NLAB + EOS_];
        return;
    }

    // ---------------- forward path ------------------------------------------
    const int w = tid >> 6;        // wave 0..3: owns M-tiles {w, w+4}
    const int l = tid & 63;
    const int a = l >> 4;          // K-chunk for A/B frags, row-chunk for C
    const int c = l & 15;          // batch column
    const int G = bx * MB + c;
    const size_t fbase = (size_t)G * TT * NLAB;

    __shared__ __align__(16) unsigned short P16[2][2048];   // P^T bf16 dbuf (8 KiB)
    __shared__ float red_s[4][MB];

    const int s0 = 4 * w + a, s1 = 4 * w + 16 + a;   // f32x4 idx within row

    // ---- 8-deep ring: slot k holds f(1+k) raw (converted to EF in-loop) ----
    f32x4 F0a, F0b, F1a, F1b, F2a, F2b, F3a, F3b,
          F4a, F4b, F5a, F5b, F6a, F6b, F7a, F7b;
    {
        const f32x4* fp = (const f32x4*)(feats + fbase);
        F0a = fp[1 * 32 + s0]; F0b = fp[1 * 32 + s1];
        F1a = fp[2 * 32 + s0]; F1b = fp[2 * 32 + s1];
        F2a = fp[3 * 32 + s0]; F2b = fp[3 * 32 + s1];
        F3a = fp[4 * 32 + s0]; F3b = fp[4 * 32 + s1];
        F4a = fp[5 * 32 + s0]; F4b = fp[5 * 32 + s1];
        F5a = fp[6 * 32 + s0]; F5b = fp[6 * 32 + s1];
        F6a = fp[7 * 32 + s0]; F6b = fp[7 * 32 + s1];
        F7a = fp[8 * 32 + s0]; F7b = fp[8 * 32 + s1];
    }

    // ---- lengths (each wave computes redundantly; no cross-wave sync) ------
    int cnt = 0;
    if (isi) {
        const uint4* mp = (const uint4*)((const int*)m8 + (size_t)G * TT + a * 128);
        #pragma unroll 8
        for (int i = 0; i < 32; ++i) {
            uint4 v = mp[i];
            cnt += (v.x != 0) + (v.y != 0) + (v.z != 0) + (v.w != 0);
        }
    } else {
        const uint4* mp = (const uint4*)(m8 + (size_t)G * TT + a * 128);
        #pragma unroll
        for (int i = 0; i < 8; ++i) {
            uint4 v = mp[i];
            cnt += (int)((((v.x & 0x01010101u) * 0x01010101u) >> 24)
                       + (((v.y & 0x01010101u) * 0x01010101u) >> 24)
                       + (((v.z & 0x01010101u) * 0x01010101u) >> 24)
                       + (((v.w & 0x01010101u) * 0x01010101u) >> 24));
        }
    }
    cnt += __shfl_xor(cnt, 16, 64);
    cnt += __shfl_xor(cnt, 32, 64);
    const int mylen = cnt;                    // len of batch c (uniform over a)
    int maxlen = mylen;
    maxlen = max(maxlen, __shfl_xor(maxlen, 1, 64));
    maxlen = max(maxlen, __shfl_xor(maxlen, 2, 64));
    maxlen = max(maxlen, __shfl_xor(maxlen, 4, 64));
    maxlen = max(maxlen, __shfl_xor(maxlen, 8, 64));
    const int mx = maxlen - 1;                // >= 255 (lengths in [T/2, T])

    // ---- loop-invariant E^T A-frags for tiles {w, w+4}: 32 VGPRs -----------
    // A[m][k] = E[k][m] = exp(tr[k][m]); lane (a,c): m = 16*mt + c,
    // k = 32*kt + 8*a + jj.
    s16x8 Af00, Af01, Af02, Af03, Af10, Af11, Af12, Af13;
    {
        s16x8* A0[4] = {&Af00, &Af01, &Af02, &Af03};
        s16x8* A1[4] = {&Af10, &Af11, &Af12, &Af13};
        #pragma unroll
        for (int kt = 0; kt < 4; ++kt)
            #pragma unroll
            for (int jj = 0; jj < 8; ++jj) {
                const float* tp = tr + (kt * 32 + a * 8 + jj) * NLAB + c;
                (*A0[kt])[jj] = (short)f2bf(__expf(tp[w * 16]));
                (*A1[kt])[jj] = (short)f2bf(__expf(tp[(w + 4) * 16]));
            }
    }

    // ---- t=0 init: u = tr[BOS,:] + feat0, normalized by label-3 value ------
    f32x4 pf0, pf1;               // lane's 8 p-values: labels 16*{w,w+4}+4a+r
    float C;
    {
        const float n0 = tr[BOS_ * NLAB + 3] + feats[fbase + 3];
        C = n0;
        const f32x4 tb0 = *(const f32x4*)(tr + BOS_ * NLAB + w * 16 + a * 4);
        const f32x4 ff0 = *(const f32x4*)(feats + fbase + w * 16 + a * 4);
        const f32x4 tb1 = *(const f32x4*)(tr + BOS_ * NLAB + (w + 4) * 16 + a * 4);
        const f32x4 ff1 = *(const f32x4*)(feats + fbase + (w + 4) * 16 + a * 4);
        #pragma unroll
        for (int r = 0; r < 4; ++r) {
            pf0[r] = __expf(tb0[r] + ff0[r] - n0);
            pf1[r] = __expf(tb1[r] + ff1[r] - n0);
        }
    }

    // B-frag LDS layout (conflict-free): addr16(k,n) = ((k>>3)*16+n)*8+(k&7)
    const int wb0 = ((2 * w       + (a >> 1)) * 16 + c) * 8 + (a & 1) * 4;
    const int wb1 = ((2 * (w + 4) + (a >> 1)) * 16 + c) * 8 + (a & 1) * 4;
    *(uint2*)&P16[0][wb0] = make_uint2(cvtpk(pf0[0], pf0[1]), cvtpk(pf0[2], pf0[3]));
    *(uint2*)&P16[0][wb1] = make_uint2(cvtpk(pf1[0], pf1[1]), cvtpk(pf1[2], pf1[3]));

    // convert slot 0 (f(1)) to EF for step 1
    #pragma unroll
    for (int r = 0; r < 4; ++r) {
        F0a[r] = EXP2F(F0a[r] * LOG2E);
        F0b[r] = EXP2F(F0b[r] * LOG2E);
    }

    const int rab = a * 16 + c;   // B-frag read element base: (kt*4+a)*16+c
    const f32x4 zac = {0.f, 0.f, 0.f, 0.f};

    // One recursion step.  Slot layout: step T consumes EF slot (T-1)&7,
    // reloads that slot <- raw f(T+8) at step TOP (full step before the next
    // barrier's vmcnt(0) drain), and converts slot T&7 raw->EF for step T+1.
    // e = exponent of bf16 p[3][batch c], read directly (broadcast ds_read_u16
    // at addr16 c*8+3) in parallel with the b-frag reads.
#define STEP(T_, Fa, Fb, Na, Nb) {                                            \
    __syncthreads();                                                          \
    const f32x4 efa = Fa, efb = Fb;        /* keep EF; slot reloads below */  \
    {   const f32x4* fp = (const f32x4*)(feats + fbase                        \
                              + (size_t)min((T_) + 8, mx) * NLAB);            \
        Fa = fp[s0]; Fb = fp[s1]; }                                           \
    const int PB = (T_) & 1;                                                  \
    const s16x8* PR = (const s16x8*)P16[1 - PB];                              \
    const s16x8 b0 = PR[rab],       b1 = PR[64 + rab],                        \
                b2 = PR[128 + rab], b3 = PR[192 + rab];                       \
    const int p3 = (int)P16[1 - PB][c * 8 + 3];                               \
    f32x4 x0 = MFMA_(Af00, b0, zac); f32x4 x1 = MFMA_(Af01, b1, zac);         \
    f32x4 x2 = MFMA_(Af02, b2, zac); f32x4 x3 = MFMA_(Af03, b3, zac);         \
    f32x4 y0 = MFMA_(Af10, b0, zac); f32x4 y1 = MFMA_(Af11, b1, zac);         \
    f32x4 y2 = MFMA_(Af12, b2, zac); f32x4 y3 = MFMA_(Af13, b3, zac);         \
    const int e = ((p3 >> 7) & 255) - 126;                                    \
    const float sc = __uint_as_float((unsigned)(127 - e) << 23);   /* 2^-e */ \
    const f32x4 acc0 = (x0 + x1) + (x2 + x3);                                 \
    const f32x4 acc1 = (y0 + y1) + (y2 + y3);                                 \
    const bool live = (T_) < mylen;                                           \
    _Pragma("unroll")                                                         \
    for (int r = 0; r < 4; ++r) {                                             \
        const float m0 = efa[r] * sc;      /* off-chain: ready pre-mfma-end */\
        const float m1 = efb[r] * sc;                                         \
        const float q0 = acc0[r] * m0;                                        \
        const float q1 = acc1[r] * m1;                                        \
        if (live) { pf0[r] = q0; pf1[r] = q1; }                               \
    }                                                                         \
    if (live) C += (float)e * LN2F;                                           \
    *(uint2*)&P16[PB][wb0] = make_uint2(cvtpk(pf0[0], pf0[1]),                \
                                        cvtpk(pf0[2], pf0[3]));               \
    *(uint2*)&P16[PB][wb1] = make_uint2(cvtpk(pf1[0], pf1[1]),                \
                                        cvtpk(pf1[2], pf1[3]));               \
    _Pragma("unroll")                                                         \
    for (int r = 0; r < 4; ++r) {       /* convert next slot raw -> EF */     \
        Na[r] = EXP2F(Na[r] * LOG2E);                                         \
        Nb[r] = EXP2F(Nb[r] * LOG2E);                                         \
    }                                                                         \
}

    #pragma unroll 1
    for (int t0 = 1; t0 < maxlen; t0 += 8) {
        const int nstep = maxlen - t0;
        STEP(t0, F0a, F0b, F1a, F1b)
        if (nstep > 1) STEP(t0 + 1, F1a, F1b, F2a, F2b)
        if (nstep > 2) STEP(t0 + 2, F2a, F2b, F3a, F3b)
        if (nstep > 3) STEP(t0 + 3, F3a, F3b, F4a, F4b)
        if (nstep > 4) STEP(t0 + 4, F4a, F4b, F5a, F5b)
        if (nstep > 5) STEP(t0 + 5, F5a, F5b, F6a, F6b)
        if (nstep > 6) STEP(t0 + 6, F6a, F6b, F7a, F7b)
        if (nstep > 7) STEP(t0 + 7, F7a, F7b, F0a, F0b)
    }
#undef STEP

    // ---- logZ_b = C + log(sum_j p[j][b] * exp(tr[j,EOS])) ------------------
    float s = 0.f;
    #pragma unroll
    for (int r = 0; r < 4; ++r) {
        s += pf0[r] * __expf(tr[(w * 16 + 4 * a + r) * NLAB + EOS_]);
        s += pf1[r] * __expf(tr[((w + 4) * 16 + 4 * a + r) * NLAB + EOS_]);
    }
    s += __shfl_xor(s, 16, 64);
    s += __shfl_xor(s, 32, 64);
    if (l < 16) red_s[w][c] = s;
    __syncthreads();
    if (tid < 16) {
        float S = red_s[0][tid] + red_s[1][tid] + red_s[2][tid] + red_s[3][tid];
        logZ_out[bx * MB + tid] = C + __logf(S);   // wave-0 lane tid: batch tid
    }
}

// ---- final reduction: out = mean(logZ - gold) ------------------------------
__global__ void crf_finalize(const float* __restrict__ gold,
                             const float* __restrict__ logZ,
                             float* __restrict__ out) {
    __shared__ float sh[4];
    const int i = threadIdx.x;  // 256 threads
    float v = (logZ[i] - gold[i]) + (logZ[i + 256] - gold[i + 256]);
    #pragma unroll
    for (int off = 32; off > 0; off >>= 1)
        v += __shfl_xor(v, off, 64);
    if ((i & 63) == 0) sh[i >> 6] = v;
    __syncthreads();
    if (i == 0) out[0] = (sh[0] + sh[1] + sh[2] + sh[3]) * (1.0f / (float)BB);
}

extern "C" void kernel_launch(void* const* d_in, const int* in_sizes, int n_in,
                              void* d_out, int out_size, void* d_ws, size_t ws_size,
                              hipStream_t stream) {
    const float*         feats = (const float*)d_in[0];
    const int*           tags  = (const int*)d_in[1];
    const unsigned char* m8    = (const unsigned char*)d_in[2];
    const float*         tr    = (const float*)d_in[3];

    float* gold = (float*)d_ws;       // 512 floats
    float* logZ = gold + BB;          // 512 floats
    float* out  = (float*)d_out;

    hipLaunchKernelGGL(crf_fused, dim3(BB / MB + BB / 4), dim3(256), 0, stream,
                       feats, tags, m8, tr, gold, logZ);
    hipLaunchKernelGGL(crf_finalize, dim3(1), dim3(256), 0, stream,
                       gold, logZ, out);
}

// Round 5
// 525.694 us; speedup vs baseline: 1.0092x; 1.0092x over previous
//
#include <hip/hip_runtime.h>
#include <cstdint>
#include <cstddef>

#define NLAB 128
#define TT   512
#define BB   512
#define MB   16        // batches per forward block
#define PAD_ 0
#define BOS_ 1
#define EOS_ 2
#define LN2F  0.6931471805599453f
#define LOG2E 1.4426950408889634f

typedef float f32x4 __attribute__((ext_vector_type(4)));
typedef short s16x8 __attribute__((ext_vector_type(8)));

#if __has_builtin(__builtin_amdgcn_exp2f)
#define EXP2F(x) __builtin_amdgcn_exp2f(x)
#else
#define EXP2F(x) exp2f(x)
#endif

#if __has_builtin(__builtin_amdgcn_sched_barrier)
#define SCHED_FENCE() __builtin_amdgcn_sched_barrier(0)
#else
#define SCHED_FENCE() asm volatile("" ::: "memory")
#endif

#define MFMA_(A,B,CV) __builtin_amdgcn_mfma_f32_16x16x32_bf16((A),(B),(CV),0,0,0)

// ---- mask dtype hedge: bool(1B) vs int32(4B) -------------------------------
__device__ __forceinline__ bool mask_is_i32(const unsigned char* m8) {
    return m8[1] == 0;   // mask[0][1] always true; int32 high byte => 0
}
__device__ __forceinline__ bool mask_at(const unsigned char* m8, int idx, bool isi) {
    if (isi) return ((const int*)m8)[idx] != 0;
    return m8[idx] != 0;
}

__device__ __forceinline__ unsigned f2bf(float f) {
    union { float f; unsigned u; } v; v.f = f;
    return (v.u + 0x7FFFu + ((v.u >> 16) & 1u)) >> 16;   // RNE; inputs finite >= 0
}
__device__ __forceinline__ unsigned cvtpk(float lo, float hi) {   // bf16 pair, RNE
    unsigned r;
    asm("v_cvt_pk_bf16_f32 %0, %1, %2" : "=v"(r) : "v"(lo), "v"(hi));
    return r;
}

// ============================================================================
// Fused kernel, 256 threads/block.
//   blocks [0, 32):    forward scan, 4 waves (1/SIMD).  Wave w owns M-tiles
//                      {w, w+4}.  One __syncthreads per step (proven).
//                      vs r4 (ONE isolated change): the per-step feature
//                      reload is PINNED at the step top with sched_barrier(0)
//                      -- r4's regression was the scheduler sinking these
//                      loads to just before the next barrier (vmcnt(0) drain
//                      -> ~900 cyc exposed EVERY step).  Pinned at top, the
//                      issue-to-drain distance is a full step => exposure ~0.
//                      Retained from r4: 8 independent MFMAs + pairwise adds;
//                      rescale exponent from bf16 p[3][c] via broadcast
//                      ds_read_u16 (parallel to b-frag reads, no serial
//                      shfl); ring slots convert raw->EF one step ahead.
//   blocks [32, 160):  gold score + length, 4 batches/block (1 per wave).
// ============================================================================
__global__ __launch_bounds__(256, 1) void crf_fused(
        const float* __restrict__ feats,
        const int*   __restrict__ tags,
        const unsigned char* __restrict__ m8,
        const float* __restrict__ tr,
        float* __restrict__ gold_out,
        float* __restrict__ logZ_out) {
    const int bx  = blockIdx.x;
    const int tid = threadIdx.x;
    const bool isi = mask_is_i32(m8);

    if (bx >= BB / MB) {
        // ---------------- gold path: 4 batches per block ---------------------
        const int b    = (bx - BB / MB) * 4 + (tid >> 6);
        const int lane = tid & 63;
        const size_t fb = (size_t)b * TT * NLAB;
        float gp = 0.f; int cnt = 0;
        for (int tt = lane; tt < TT; tt += 64) {
            const int idx = b * TT + tt;
            const bool mm = mask_at(m8, idx, isi);
            cnt += mm ? 1 : 0;
            const int tg = tags[idx];
            if (tt == 0) gp += feats[fb + tg] + tr[BOS_ * NLAB + tg];
            else if (mm) gp += feats[fb + (size_t)tt * NLAB + tg]
                             + tr[tags[idx - 1] * NLAB + tg];
        }
        #pragma unroll
        for (int off = 32; off > 0; off >>= 1) {
            gp  += __shfl_xor(gp,  off, 64);
            cnt += __shfl_xor(cnt, off, 64);
        }
        if (lane == 0)
            gold_out[b] = gp + tr[tags[b * TT + cnt - 1] * NLAB + EOS_];
        return;
    }

    // ---------------- forward path ------------------------------------------
    const int w = tid >> 6;        // wave 0..3: owns M-tiles {w, w+4}
    const int l = tid & 63;
    const int a = l >> 4;          // K-chunk for A/B frags, row-chunk for C
    const int c = l & 15;          // batch column
    const int G = bx * MB + c;
    const size_t fbase = (size_t)G * TT * NLAB;

    __shared__ __align__(16) unsigned short P16[2][2048];   // P^T bf16 dbuf (8 KiB)
    __shared__ float red_s[4][MB];

    const int s0 = 4 * w + a, s1 = 4 * w + 16 + a;   // f32x4 idx within row

    // ---- 8-deep ring: slot k holds f(1+k) raw (converted to EF in-loop) ----
    f32x4 F0a, F0b, F1a, F1b, F2a, F2b, F3a, F3b,
          F4a, F4b, F5a, F5b, F6a, F6b, F7a, F7b;
    {
        const f32x4* fp = (const f32x4*)(feats + fbase);
        F0a = fp[1 * 32 + s0]; F0b = fp[1 * 32 + s1];
        F1a = fp[2 * 32 + s0]; F1b = fp[2 * 32 + s1];
        F2a = fp[3 * 32 + s0]; F2b = fp[3 * 32 + s1];
        F3a = fp[4 * 32 + s0]; F3b = fp[4 * 32 + s1];
        F4a = fp[5 * 32 + s0]; F4b = fp[5 * 32 + s1];
        F5a = fp[6 * 32 + s0]; F5b = fp[6 * 32 + s1];
        F6a = fp[7 * 32 + s0]; F6b = fp[7 * 32 + s1];
        F7a = fp[8 * 32 + s0]; F7b = fp[8 * 32 + s1];
    }

    // ---- lengths (each wave computes redundantly; no cross-wave sync) ------
    int cnt = 0;
    if (isi) {
        const uint4* mp = (const uint4*)((const int*)m8 + (size_t)G * TT + a * 128);
        #pragma unroll 8
        for (int i = 0; i < 32; ++i) {
            uint4 v = mp[i];
            cnt += (v.x != 0) + (v.y != 0) + (v.z != 0) + (v.w != 0);
        }
    } else {
        const uint4* mp = (const uint4*)(m8 + (size_t)G * TT + a * 128);
        #pragma unroll
        for (int i = 0; i < 8; ++i) {
            uint4 v = mp[i];
            cnt += (int)((((v.x & 0x01010101u) * 0x01010101u) >> 24)
                       + (((v.y & 0x01010101u) * 0x01010101u) >> 24)
                       + (((v.z & 0x01010101u) * 0x01010101u) >> 24)
                       + (((v.w & 0x01010101u) * 0x01010101u) >> 24));
        }
    }
    cnt += __shfl_xor(cnt, 16, 64);
    cnt += __shfl_xor(cnt, 32, 64);
    const int mylen = cnt;                    // len of batch c (uniform over a)
    int maxlen = mylen;
    maxlen = max(maxlen, __shfl_xor(maxlen, 1, 64));
    maxlen = max(maxlen, __shfl_xor(maxlen, 2, 64));
    maxlen = max(maxlen, __shfl_xor(maxlen, 4, 64));
    maxlen = max(maxlen, __shfl_xor(maxlen, 8, 64));
    const int mx = maxlen - 1;                // >= 255 (lengths in [T/2, T])

    // ---- loop-invariant E^T A-frags for tiles {w, w+4}: 32 VGPRs -----------
    // A[m][k] = E[k][m] = exp(tr[k][m]); lane (a,c): m = 16*mt + c,
    // k = 32*kt + 8*a + jj.
    s16x8 Af00, Af01, Af02, Af03, Af10, Af11, Af12, Af13;
    {
        s16x8* A0[4] = {&Af00, &Af01, &Af02, &Af03};
        s16x8* A1[4] = {&Af10, &Af11, &Af12, &Af13};
        #pragma unroll
        for (int kt = 0; kt < 4; ++kt)
            #pragma unroll
            for (int jj = 0; jj < 8; ++jj) {
                const float* tp = tr + (kt * 32 + a * 8 + jj) * NLAB + c;
                (*A0[kt])[jj] = (short)f2bf(__expf(tp[w * 16]));
                (*A1[kt])[jj] = (short)f2bf(__expf(tp[(w + 4) * 16]));
            }
    }

    // ---- t=0 init: u = tr[BOS,:] + feat0, normalized by label-3 value ------
    f32x4 pf0, pf1;               // lane's 8 p-values: labels 16*{w,w+4}+4a+r
    float C;
    {
        const float n0 = tr[BOS_ * NLAB + 3] + feats[fbase + 3];
        C = n0;
        const f32x4 tb0 = *(const f32x4*)(tr + BOS_ * NLAB + w * 16 + a * 4);
        const f32x4 ff0 = *(const f32x4*)(feats + fbase + w * 16 + a * 4);
        const f32x4 tb1 = *(const f32x4*)(tr + BOS_ * NLAB + (w + 4) * 16 + a * 4);
        const f32x4 ff1 = *(const f32x4*)(feats + fbase + (w + 4) * 16 + a * 4);
        #pragma unroll
        for (int r = 0; r < 4; ++r) {
            pf0[r] = __expf(tb0[r] + ff0[r] - n0);
            pf1[r] = __expf(tb1[r] + ff1[r] - n0);
        }
    }

    // B-frag LDS layout (conflict-free): addr16(k,n) = ((k>>3)*16+n)*8+(k&7)
    const int wb0 = ((2 * w       + (a >> 1)) * 16 + c) * 8 + (a & 1) * 4;
    const int wb1 = ((2 * (w + 4) + (a >> 1)) * 16 + c) * 8 + (a & 1) * 4;
    *(uint2*)&P16[0][wb0] = make_uint2(cvtpk(pf0[0], pf0[1]), cvtpk(pf0[2], pf0[3]));
    *(uint2*)&P16[0][wb1] = make_uint2(cvtpk(pf1[0], pf1[1]), cvtpk(pf1[2], pf1[3]));

    // convert slot 0 (f(1)) to EF for step 1
    #pragma unroll
    for (int r = 0; r < 4; ++r) {
        F0a[r] = EXP2F(F0a[r] * LOG2E);
        F0b[r] = EXP2F(F0b[r] * LOG2E);
    }

    const int rab = a * 16 + c;   // B-frag read element base: (kt*4+a)*16+c
    const f32x4 zac = {0.f, 0.f, 0.f, 0.f};

    // One recursion step.  Step T consumes EF slot (T-1)&7, reloads that slot
    // <- raw f(T+8) PINNED AT STEP TOP (sched_barrier(0) stops the scheduler
    // sinking the loads to just-before-the-next-barrier, which is what made
    // r4 regress), and converts slot T&7 raw->EF for step T+1.  e = exponent
    // of bf16 p[3][batch c], read via broadcast ds_read_u16 in parallel with
    // the b-frag reads.  Any e is self-consistent (q*2^-e pairs with C+=e*ln2).
#define STEP(T_, Fa, Fb, Na, Nb) {                                            \
    __syncthreads();                                                          \
    const f32x4 efa = Fa, efb = Fb;        /* keep EF; slot reloads below */  \
    {   const f32x4* fp = (const f32x4*)(feats + fbase                        \
                              + (size_t)min((T_) + 8, mx) * NLAB);            \
        Fa = fp[s0]; Fb = fp[s1]; }                                           \
    SCHED_FENCE();                         /* loads may NOT sink past here */ \
    const int PB = (T_) & 1;                                                  \
    const s16x8* PR = (const s16x8*)P16[1 - PB];                              \
    const s16x8 b0 = PR[rab],       b1 = PR[64 + rab],                        \
                b2 = PR[128 + rab], b3 = PR[192 + rab];                       \
    const int p3 = (int)P16[1 - PB][c * 8 + 3];                               \
    f32x4 x0 = MFMA_(Af00, b0, zac); f32x4 x1 = MFMA_(Af01, b1, zac);         \
    f32x4 x2 = MFMA_(Af02, b2, zac); f32x4 x3 = MFMA_(Af03, b3, zac);         \
    f32x4 y0 = MFMA_(Af10, b0, zac); f32x4 y1 = MFMA_(Af11, b1, zac);         \
    f32x4 y2 = MFMA_(Af12, b2, zac); f32x4 y3 = MFMA_(Af13, b3, zac);         \
    const int e = ((p3 >> 7) & 255) - 126;                                    \
    const float sc = __uint_as_float((unsigned)(127 - e) << 23);   /* 2^-e */ \
    const f32x4 acc0 = (x0 + x1) + (x2 + x3);                                 \
    const f32x4 acc1 = (y0 + y1) + (y2 + y3);                                 \
    const bool live = (T_) < mylen;                                           \
    _Pragma("unroll")                                                         \
    for (int r = 0; r < 4; ++r) {                                             \
        const float m0 = efa[r] * sc;      /* off-chain: ready pre-mfma-end */\
        const float m1 = efb[r] * sc;                                         \
        const float q0 = acc0[r] * m0;                                        \
        const float q1 = acc1[r] * m1;                                        \
        if (live) { pf0[r] = q0; pf1[r] = q1; }                               \
    }                                                                         \
    if (live) C += (float)e * LN2F;                                           \
    *(uint2*)&P16[PB][wb0] = make_uint2(cvtpk(pf0[0], pf0[1]),                \
                                        cvtpk(pf0[2], pf0[3]));               \
    *(uint2*)&P16[PB][wb1] = make_uint2(cvtpk(pf1[0], pf1[1]),                \
                                        cvtpk(pf1[2], pf1[3]));               \
    _Pragma("unroll")                                                         \
    for (int r = 0; r < 4; ++r) {       /* convert next slot raw -> EF */     \
        Na[r] = EXP2F(Na[r] * LOG2E);                                         \
        Nb[r] = EXP2F(Nb[r] * LOG2E);                                         \
    }                                                                         \
}

    #pragma unroll 1
    for (int t0 = 1; t0 < maxlen; t0 += 8) {
        const int nstep = maxlen - t0;
        STEP(t0, F0a, F0b, F1a, F1b)
        if (nstep > 1) STEP(t0 + 1, F1a, F1b, F2a, F2b)
        if (nstep > 2) STEP(t0 + 2, F2a, F2b, F3a, F3b)
        if (nstep > 3) STEP(t0 + 3, F3a, F3b, F4a, F4b)
        if (nstep > 4) STEP(t0 + 4, F4a, F4b, F5a, F5b)
        if (nstep > 5) STEP(t0 + 5, F5a, F5b, F6a, F6b)
        if (nstep > 6) STEP(t0 + 6, F6a, F6b, F7a, F7b)
        if (nstep > 7) STEP(t0 + 7, F7a, F7b, F0a, F0b)
    }
#undef STEP

    // ---- logZ_b = C + log(sum_j p[j][b] * exp(tr[j,EOS])) ------------------
    float s = 0.f;
    #pragma unroll
    for (int r = 0; r < 4; ++r) {
        s += pf0[r] * __expf(tr[(w * 16 + 4 * a + r) * NLAB + EOS_]);
        s += pf1[r] * __expf(tr[((w + 4) * 16 + 4 * a + r) * NLAB + EOS_]);
    }
    s += __shfl_xor(s, 16, 64);
    s += __shfl_xor(s, 32, 64);
    if (l < 16) red_s[w][c] = s;
    __syncthreads();
    if (tid < 16) {
        float S = red_s[0][tid] + red_s[1][tid] + red_s[2][tid] + red_s[3][tid];
        logZ_out[bx * MB + tid] = C + __logf(S);   // wave-0 lane tid: batch tid
    }
}

// ---- final reduction: out = mean(logZ - gold) ------------------------------
__global__ void crf_finalize(const float* __restrict__ gold,
                             const float* __restrict__ logZ,
                             float* __restrict__ out) {
    __shared__ float sh[4];
    const int i = threadIdx.x;  // 256 threads
    float v = (logZ[i] - gold[i]) + (logZ[i + 256] - gold[i + 256]);
    #pragma unroll
    for (int off = 32; off > 0; off >>= 1)
        v += __shfl_xor(v, off, 64);
    if ((i & 63) == 0) sh[i >> 6] = v;
    __syncthreads();
    if (i == 0) out[0] = (sh[0] + sh[1] + sh[2] + sh[3]) * (1.0f / (float)BB);
}

extern "C" void kernel_launch(void* const* d_in, const int* in_sizes, int n_in,
                              void* d_out, int out_size, void* d_ws, size_t ws_size,
                              hipStream_t stream) {
    const float*         feats = (const float*)d_in[0];
    const int*           tags  = (const int*)d_in[1];
    const unsigned char* m8    = (const unsigned char*)d_in[2];
    const float*         tr    = (const float*)d_in[3];

    float* gold = (float*)d_ws;       // 512 floats
    float* logZ = gold + BB;          // 512 floats
    float* out  = (float*)d_out;

    hipLaunchKernelGGL(crf_fused, dim3(BB / MB + BB / 4), dim3(256), 0, stream,
                       feats, tags, m8, tr, gold, logZ);
    hipLaunchKernelGGL(crf_finalize, dim3(1), dim3(256), 0, stream,
                       gold, logZ, out);
}

// Round 6
// 424.298 us; speedup vs baseline: 1.2504x; 1.2390x over previous
//
#include <hip/hip_runtime.h>
#include <cstdint>
#include <cstddef>

#define NLAB 128
#define TT   512
#define BB   512
#define MB   16        // batches per forward block
#define PAD_ 0
#define BOS_ 1
#define EOS_ 2
#define LN2F  0.6931471805599453f
#define LOG2E 1.4426950408889634f

typedef float f32x4 __attribute__((ext_vector_type(4)));
typedef short s16x8 __attribute__((ext_vector_type(8)));

#if __has_builtin(__builtin_amdgcn_exp2f)
#define EXP2F(x) __builtin_amdgcn_exp2f(x)
#else
#define EXP2F(x) exp2f(x)
#endif

#if __has_builtin(__builtin_amdgcn_sched_barrier)
#define SCHED_FENCE() __builtin_amdgcn_sched_barrier(0)
#else
#define SCHED_FENCE() asm volatile("" ::: "memory")
#endif

// m201-proven loop barrier: publish my LDS writes, sync waves, do NOT drain
// vmcnt (global loads stay in flight across barriers).  sched_barrier(0) on
// both sides prevents rule-#18 hoisting (r2's failure mode).
#define WAVE_BARRIER() do {                                                   \
    asm volatile("s_waitcnt lgkmcnt(0)" ::: "memory");                        \
    SCHED_FENCE();                                                            \
    __builtin_amdgcn_s_barrier();                                             \
    SCHED_FENCE();                                                            \
} while (0)

#define MFMA_(A,B,CV) __builtin_amdgcn_mfma_f32_16x16x32_bf16((A),(B),(CV),0,0,0)

// ---- mask dtype hedge: bool(1B) vs int32(4B) -------------------------------
__device__ __forceinline__ bool mask_is_i32(const unsigned char* m8) {
    return m8[1] == 0;   // mask[0][1] always true; int32 high byte => 0
}
__device__ __forceinline__ bool mask_at(const unsigned char* m8, int idx, bool isi) {
    if (isi) return ((const int*)m8)[idx] != 0;
    return m8[idx] != 0;
}

__device__ __forceinline__ unsigned f2bf(float f) {
    union { float f; unsigned u; } v; v.f = f;
    return (v.u + 0x7FFFu + ((v.u >> 16) & 1u)) >> 16;   // RNE; inputs finite >= 0
}
__device__ __forceinline__ unsigned cvtpk(float lo, float hi) {   // bf16 pair, RNE
    unsigned r;
    asm("v_cvt_pk_bf16_f32 %0, %1, %2" : "=v"(r) : "v"(lo), "v"(hi));
    return r;
}

// ============================================================================
// Fused kernel, 256 threads/block.  Round-3 body (proven 292 us forward,
// absmax 0.0) with TWO changes:
//   (1) in-loop __syncthreads -> WAVE_BARRIER(): lgkmcnt(0)+s_barrier only.
//       __syncthreads emits s_waitcnt vmcnt(0) expcnt(0) lgkmcnt(0)+s_barrier,
//       force-draining the feature burst loads every step.  With the raw
//       barrier the loads coast; the compiler's automatic counted vmcnt at
//       each ring slot's first use (>= 1 full step later) covers them.
//   (2) rescale exponent e read via broadcast ds_read_u16 of bf16 p[3][c]
//       (numerics proven r4/r5) instead of serial __shfl off b0 (~120 cyc).
//   blocks [32, 160):  gold score + length, 4 batches/block (1 per wave).
// ============================================================================
__global__ __launch_bounds__(256, 1) void crf_fused(
        const float* __restrict__ feats,
        const int*   __restrict__ tags,
        const unsigned char* __restrict__ m8,
        const float* __restrict__ tr,
        float* __restrict__ gold_out,
        float* __restrict__ logZ_out) {
    const int bx  = blockIdx.x;
    const int tid = threadIdx.x;
    const bool isi = mask_is_i32(m8);

    if (bx >= BB / MB) {
        // ---------------- gold path: 4 batches per block ---------------------
        const int b    = (bx - BB / MB) * 4 + (tid >> 6);
        const int lane = tid & 63;
        const size_t fb = (size_t)b * TT * NLAB;
        float gp = 0.f; int cnt = 0;
        for (int tt = lane; tt < TT; tt += 64) {
            const int idx = b * TT + tt;
            const bool mm = mask_at(m8, idx, isi);
            cnt += mm ? 1 : 0;
            const int tg = tags[idx];
            if (tt == 0) gp += feats[fb + tg] + tr[BOS_ * NLAB + tg];
            else if (mm) gp += feats[fb + (size_t)tt * NLAB + tg]
                             + tr[tags[idx - 1] * NLAB + tg];
        }
        #pragma unroll
        for (int off = 32; off > 0; off >>= 1) {
            gp  += __shfl_xor(gp,  off, 64);
            cnt += __shfl_xor(cnt, off, 64);
        }
        if (lane == 0)
            gold_out[b] = gp + tr[tags[b * TT + cnt - 1] * NLAB + EOS_];
        return;
    }

    // ---------------- forward path ------------------------------------------
    const int w = tid >> 6;        // wave 0..3: owns M-tiles {w, w+4}
    const int l = tid & 63;
    const int a = l >> 4;          // K-chunk for A/B frags, row-chunk for C
    const int c = l & 15;          // batch column
    const int G = bx * MB + c;
    const size_t fbase = (size_t)G * TT * NLAB;

    __shared__ __align__(16) unsigned short P16[2][2048];   // P^T bf16 dbuf (8 KiB)
    __shared__ float red_s[4][MB];

    const int s0 = 4 * w + a, s1 = 4 * w + 16 + a;   // f32x4 idx within row

    // ---- 8-deep feature ring, prologue fill t=1..8 (always valid: < TT) ----
    f32x4 F0a, F0b, F1a, F1b, F2a, F2b, F3a, F3b,
          F4a, F4b, F5a, F5b, F6a, F6b, F7a, F7b;
    {
        const f32x4* fp = (const f32x4*)(feats + fbase);
        F0a = fp[1 * 32 + s0]; F0b = fp[1 * 32 + s1];
        F1a = fp[2 * 32 + s0]; F1b = fp[2 * 32 + s1];
        F2a = fp[3 * 32 + s0]; F2b = fp[3 * 32 + s1];
        F3a = fp[4 * 32 + s0]; F3b = fp[4 * 32 + s1];
        F4a = fp[5 * 32 + s0]; F4b = fp[5 * 32 + s1];
        F5a = fp[6 * 32 + s0]; F5b = fp[6 * 32 + s1];
        F6a = fp[7 * 32 + s0]; F6b = fp[7 * 32 + s1];
        F7a = fp[8 * 32 + s0]; F7b = fp[8 * 32 + s1];
    }

    // ---- lengths (each wave computes redundantly; no cross-wave sync) ------
    int cnt = 0;
    if (isi) {
        const uint4* mp = (const uint4*)((const int*)m8 + (size_t)G * TT + a * 128);
        #pragma unroll 8
        for (int i = 0; i < 32; ++i) {
            uint4 v = mp[i];
            cnt += (v.x != 0) + (v.y != 0) + (v.z != 0) + (v.w != 0);
        }
    } else {
        const uint4* mp = (const uint4*)(m8 + (size_t)G * TT + a * 128);
        #pragma unroll
        for (int i = 0; i < 8; ++i) {
            uint4 v = mp[i];
            cnt += (int)((((v.x & 0x01010101u) * 0x01010101u) >> 24)
                       + (((v.y & 0x01010101u) * 0x01010101u) >> 24)
                       + (((v.z & 0x01010101u) * 0x01010101u) >> 24)
                       + (((v.w & 0x01010101u) * 0x01010101u) >> 24));
        }
    }
    cnt += __shfl_xor(cnt, 16, 64);
    cnt += __shfl_xor(cnt, 32, 64);
    const int mylen = cnt;                    // len of batch c (uniform over a)
    int maxlen = mylen;
    maxlen = max(maxlen, __shfl_xor(maxlen, 1, 64));
    maxlen = max(maxlen, __shfl_xor(maxlen, 2, 64));
    maxlen = max(maxlen, __shfl_xor(maxlen, 4, 64));
    maxlen = max(maxlen, __shfl_xor(maxlen, 8, 64));
    const int mx = maxlen - 1;                // >= 255 (lengths in [T/2, T])

    // ---- loop-invariant E^T A-frags for tiles {w, w+4}: 32 VGPRs -----------
    // A[m][k] = E[k][m] = exp(tr[k][m]); lane (a,c): m = 16*mt + c,
    // k = 32*kt + 8*a + jj.
    s16x8 Af00, Af01, Af02, Af03, Af10, Af11, Af12, Af13;
    {
        s16x8* A0[4] = {&Af00, &Af01, &Af02, &Af03};
        s16x8* A1[4] = {&Af10, &Af11, &Af12, &Af13};
        #pragma unroll
        for (int kt = 0; kt < 4; ++kt)
            #pragma unroll
            for (int jj = 0; jj < 8; ++jj) {
                const float* tp = tr + (kt * 32 + a * 8 + jj) * NLAB + c;
                (*A0[kt])[jj] = (short)f2bf(__expf(tp[w * 16]));
                (*A1[kt])[jj] = (short)f2bf(__expf(tp[(w + 4) * 16]));
            }
    }

    // ---- t=0 init: u = tr[BOS,:] + feat0, normalized by label-3 value ------
    f32x4 pf0, pf1;               // lane's 8 p-values: labels 16*{w,w+4}+4a+r
    float C;
    {
        const float n0 = tr[BOS_ * NLAB + 3] + feats[fbase + 3];
        C = n0;
        const f32x4 tb0 = *(const f32x4*)(tr + BOS_ * NLAB + w * 16 + a * 4);
        const f32x4 ff0 = *(const f32x4*)(feats + fbase + w * 16 + a * 4);
        const f32x4 tb1 = *(const f32x4*)(tr + BOS_ * NLAB + (w + 4) * 16 + a * 4);
        const f32x4 ff1 = *(const f32x4*)(feats + fbase + (w + 4) * 16 + a * 4);
        #pragma unroll
        for (int r = 0; r < 4; ++r) {
            pf0[r] = __expf(tb0[r] + ff0[r] - n0);
            pf1[r] = __expf(tb1[r] + ff1[r] - n0);
        }
    }

    // B-frag LDS layout (conflict-free): addr16(k,n) = ((k>>3)*16+n)*8+(k&7)
    const int wb0 = ((2 * w       + (a >> 1)) * 16 + c) * 8 + (a & 1) * 4;
    const int wb1 = ((2 * (w + 4) + (a >> 1)) * 16 + c) * 8 + (a & 1) * 4;
    *(uint2*)&P16[0][wb0] = make_uint2(cvtpk(pf0[0], pf0[1]), cvtpk(pf0[2], pf0[3]));
    *(uint2*)&P16[0][wb1] = make_uint2(cvtpk(pf1[0], pf1[1]), cvtpk(pf1[2], pf1[3]));
    __syncthreads();              // prologue publish (full sync once is fine)

    const int rab = a * 16 + c;   // B-frag read element base: (kt*4+a)*16+c
    const f32x4 zac = {0.f, 0.f, 0.f, 0.f};

    // One recursion step.  WAVE_BARRIER at top publishes the previous step's
    // write (init write for step 1 via the prologue __syncthreads).  e =
    // exponent of bf16 p[3][batch c] via broadcast ds_read_u16 at addr16
    // c*8+3 (k=3,n=c) -- off the serial chain; any e is self-consistent
    // (q*2^-e pairs with C += e*ln2).
#define STEP(T_, Fa, Fb) {                                                    \
    const int PB = (T_) & 1;                                                  \
    const s16x8* PR = (const s16x8*)P16[1 - PB];                              \
    const s16x8 b0 = PR[rab],       b1 = PR[64 + rab],                        \
                b2 = PR[128 + rab], b3 = PR[192 + rab];                       \
    const int p3 = (int)P16[1 - PB][c * 8 + 3];                               \
    const int e = ((p3 >> 7) & 255) - 126;                                    \
    f32x4 x0 = MFMA_(Af00, b0, zac); x0 = MFMA_(Af01, b1, x0);                \
    f32x4 y0 = MFMA_(Af02, b2, zac); y0 = MFMA_(Af03, b3, y0);                \
    f32x4 x1 = MFMA_(Af10, b0, zac); x1 = MFMA_(Af11, b1, x1);                \
    f32x4 y1 = MFMA_(Af12, b2, zac); y1 = MFMA_(Af13, b3, y1);                \
    const float sc = __uint_as_float((unsigned)(127 - e) << 23);   /* 2^-e */ \
    const f32x4 acc0 = x0 + y0, acc1 = x1 + y1;                               \
    const bool live = (T_) < mylen;                                           \
    _Pragma("unroll")                                                         \
    for (int r = 0; r < 4; ++r) {                                             \
        const float q0 = acc0[r] * (EXP2F(Fa[r] * LOG2E) * sc);               \
        const float q1 = acc1[r] * (EXP2F(Fb[r] * LOG2E) * sc);               \
        if (live) { pf0[r] = q0; pf1[r] = q1; }                               \
    }                                                                         \
    if (live) C += (float)e * LN2F;                                           \
    *(uint2*)&P16[PB][wb0] = make_uint2(cvtpk(pf0[0], pf0[1]),                \
                                        cvtpk(pf0[2], pf0[3]));               \
    *(uint2*)&P16[PB][wb1] = make_uint2(cvtpk(pf1[0], pf1[1]),                \
                                        cvtpk(pf1[2], pf1[3]));               \
    WAVE_BARRIER();                                                           \
}

    #pragma unroll 1
    for (int t0 = 1; t0 < maxlen; t0 += 8) {
        const int nstep = maxlen - t0;
        STEP(t0, F0a, F0b)
        if (nstep > 1) STEP(t0 + 1, F1a, F1b)
        if (nstep > 2) STEP(t0 + 2, F2a, F2b)
        if (nstep > 3) STEP(t0 + 3, F3a, F3b)
        if (nstep > 4) STEP(t0 + 4, F4a, F4b)
        if (nstep > 5) STEP(t0 + 5, F5a, F5b)
        if (nstep > 6) STEP(t0 + 6, F6a, F6b)
        if (nstep > 7) STEP(t0 + 7, F7a, F7b)
        if (t0 + 8 < maxlen) {      // burst refill; loads coast across raw barriers
            const f32x4* fp;
#define RF(i, Xa, Xb)                                                         \
            fp = (const f32x4*)(feats + fbase                                 \
                     + (size_t)min(t0 + 8 + (i), mx) * NLAB);                 \
            Xa = fp[s0]; Xb = fp[s1];
            RF(0, F0a, F0b) RF(1, F1a, F1b) RF(2, F2a, F2b) RF(3, F3a, F3b)
            RF(4, F4a, F4b) RF(5, F5a, F5b) RF(6, F6a, F6b) RF(7, F7a, F7b)
#undef RF
        }
    }
#undef STEP

    // ---- logZ_b = C + log(sum_j p[j][b] * exp(tr[j,EOS])) ------------------
    float s = 0.f;
    #pragma unroll
    for (int r = 0; r < 4; ++r) {
        s += pf0[r] * __expf(tr[(w * 16 + 4 * a + r) * NLAB + EOS_]);
        s += pf1[r] * __expf(tr[((w + 4) * 16 + 4 * a + r) * NLAB + EOS_]);
    }
    s += __shfl_xor(s, 16, 64);
    s += __shfl_xor(s, 32, 64);
    if (l < 16) red_s[w][c] = s;
    __syncthreads();
    if (tid < 16) {
        float S = red_s[0][tid] + red_s[1][tid] + red_s[2][tid] + red_s[3][tid];
        logZ_out[bx * MB + tid] = C + __logf(S);   // wave-0 lane tid: batch tid
    }
}

// ---- final reduction: out = mean(logZ - gold) ------------------------------
__global__ void crf_finalize(const float* __restrict__ gold,
                             const float* __restrict__ logZ,
                             float* __restrict__ out) {
    __shared__ float sh[4];
    const int i = threadIdx.x;  // 256 threads
    float v = (logZ[i] - gold[i]) + (logZ[i + 256] - gold[i + 256]);
    #pragma unroll
    for (int off = 32; off > 0; off >>= 1)
        v += __shfl_xor(v, off, 64);
    if ((i & 63) == 0) sh[i >> 6] = v;
    __syncthreads();
    if (i == 0) out[0] = (sh[0] + sh[1] + sh[2] + sh[3]) * (1.0f / (float)BB);
}

extern "C" void kernel_launch(void* const* d_in, const int* in_sizes, int n_in,
                              void* d_out, int out_size, void* d_ws, size_t ws_size,
                              hipStream_t stream) {
    const float*         feats = (const float*)d_in[0];
    const int*           tags  = (const int*)d_in[1];
    const unsigned char* m8    = (const unsigned char*)d_in[2];
    const float*         tr    = (const float*)d_in[3];

    float* gold = (float*)d_ws;       // 512 floats
    float* logZ = gold + BB;          // 512 floats
    float* out  = (float*)d_out;

    hipLaunchKernelGGL(crf_fused, dim3(BB / MB + BB / 4), dim3(256), 0, stream,
                       feats, tags, m8, tr, gold, logZ);
    hipLaunchKernelGGL(crf_finalize, dim3(1), dim3(256), 0, stream,
                       gold, logZ, out);
}